// Round 1
// baseline (134.289 us; speedup 1.0000x reference)
//
#include <hip/hip_runtime.h>

// Problem constants (from reference setup): m=4, h=16, t=1024, d=128, MAX_REL=128.
constexpr int D_DIM = 128;
constexpr int T_Q   = 1024;
constexpr int NPE   = 257;               // 2*MAX_REL + 1 pe rows
constexpr int WAVES = 8;                 // 512-thread block
constexpr int RPW   = 4;                 // rows per wave per iteration
constexpr int BLOCK_THREADS  = WAVES * 64;
constexpr int ROWS_PER_BLOCK = 256;      // 65536 rows / 256 blocks

// LDS: pe (rotated) 131.6 KB + per-wave Q 16 KB + per-wave rel scratch 8 KB = 156.2 KB (<160 KB)
__global__ __launch_bounds__(BLOCK_THREADS, 1)
void rpe_fused(const float* __restrict__ Q,
               const float* __restrict__ pe,
               float* __restrict__ out)
{
    // pe row r element d stored at pe_lds[r*128 + ((d + (r>>2)) & 127)]:
    //  - read (lane l reads rows 4l..4l+3 at logical d): bank = (d+l)%32 -> 2 lanes/bank, free
    //  - staging write (consecutive threads = consecutive d): banks consecutive, free
    __shared__ float pe_lds[NPE * 128];
    __shared__ float q_lds[WAVES][RPW][D_DIM];
    __shared__ float scratch[WAVES][256];

    const int tid = threadIdx.x;
    const int w   = tid >> 6;
    const int l   = tid & 63;

    // ---- stage pe into LDS (once per block) ----
    for (int flat = tid; flat < NPE * 128; flat += BLOCK_THREADS) {
        const int r = flat >> 7;
        const int d = flat & 127;
        pe_lds[r * 128 + ((d + (r >> 2)) & 127)] = pe[flat];
    }
    __syncthreads();

    const int rowBase = blockIdx.x * ROWS_PER_BLOCK;

    for (int it = 0; it < ROWS_PER_BLOCK / (WAVES * RPW); ++it) {
        const int gRow0 = rowBase + it * (WAVES * RPW) + w * RPW;

        // ---- stage this wave's 4 Q rows into LDS (wave-local; no block barrier) ----
        {
            const int rr = l >> 4;            // 0..3 (row within group)
            const int d0 = (l & 15) * 8;      // 0,8,...,120
            const float4* src = reinterpret_cast<const float4*>(Q + (size_t)(gRow0 + rr) * D_DIM + d0);
            float4 a = src[0];
            float4 b = src[1];
            float4* dst = reinterpret_cast<float4*>(&q_lds[w][rr][d0]);
            dst[0] = a;
            dst[1] = b;
        }
        // cross-lane LDS visibility within the wave (DS pipe is in-order per wave)
        asm volatile("s_waitcnt lgkmcnt(0)" ::: "memory");

        // ---- compute rel[j] for j = 4l..4l+3 over 4 rows (16 accumulators) ----
        float acc[RPW][4];
        #pragma unroll
        for (int r = 0; r < RPW; ++r)
            #pragma unroll
            for (int j = 0; j < 4; ++j) acc[r][j] = 0.f;

        const int pbase = (4 * l) * 128;
        #pragma unroll 8
        for (int d = 0; d < 128; ++d) {
            const int dr = (d + l) & 127;               // rotation (j>>2) == l for all 4 j's
            const float p0 = pe_lds[pbase + 0 * 128 + dr];
            const float p1 = pe_lds[pbase + 1 * 128 + dr];
            const float p2 = pe_lds[pbase + 2 * 128 + dr];
            const float p3 = pe_lds[pbase + 3 * 128 + dr];
            #pragma unroll
            for (int r = 0; r < RPW; ++r) {
                const float qv = q_lds[w][r][d];        // broadcast read
                acc[r][0] = fmaf(qv, p0, acc[r][0]);
                acc[r][1] = fmaf(qv, p1, acc[r][1]);
                acc[r][2] = fmaf(qv, p2, acc[r][2]);
                acc[r][3] = fmaf(qv, p3, acc[r][3]);
            }
        }

        // ---- rel[256] per row via wave reduction (lanes split d) ----
        float rel256[RPW];
        {
            const float pa = pe_lds[256 * 128 + ((l + 64) & 127)];  // pe[256][l]
            const float pb = pe_lds[256 * 128 + l];                 // pe[256][l+64]
            #pragma unroll
            for (int r = 0; r < RPW; ++r) {
                float part = q_lds[w][r][l] * pa + q_lds[w][r][l + 64] * pb;
                #pragma unroll
                for (int off = 32; off; off >>= 1)
                    part += __shfl_xor(part, off, 64);
                rel256[r] = part;
            }
        }

        // ---- per row: spill window to LDS, clamped gather, coalesced float4 stores ----
        #pragma unroll 1
        for (int r = 0; r < RPW; ++r) {
            float4* sw = reinterpret_cast<float4*>(&scratch[w][4 * l]);
            *sw = make_float4(acc[r][0], acc[r][1], acc[r][2], acc[r][3]);
            asm volatile("s_waitcnt lgkmcnt(0)" ::: "memory");

            const int gRow = gRow0 + r;
            const int t = gRow & (T_Q - 1);
            float* orow = out + (size_t)gRow * T_Q;
            const float r256 = rel256[r];

            #pragma unroll
            for (int k = 0; k < 4; ++k) {
                const int s0 = k * 256 + 4 * l;
                float v[4];
                #pragma unroll
                for (int c = 0; c < 4; ++c) {
                    const int jraw = t - (s0 + c) + 128;     // idx before clip
                    int jc = jraw < 0 ? 0 : (jraw > 255 ? 255 : jraw);
                    float x = scratch[w][jc];
                    v[c] = (jraw >= 256) ? r256 : x;         // left-clip region -> rel[256]
                }
                reinterpret_cast<float4*>(orow)[s0 >> 2] =
                    make_float4(v[0], v[1], v[2], v[3]);
            }
            // DS pipe in-order per wave: next r's scratch write cannot pass these reads
        }
    }
}

extern "C" void kernel_launch(void* const* d_in, const int* in_sizes, int n_in,
                              void* d_out, int out_size, void* d_ws, size_t ws_size,
                              hipStream_t stream)
{
    const float* Q  = (const float*)d_in[0];
    // d_in[1] is K: only its shape (t_k = 1024) matters, data unused.
    const float* pe = (const float*)d_in[2];
    float* out = (float*)d_out;

    const int total_rows = in_sizes[0] / D_DIM;        // m*h*t = 65536
    const int grid = total_rows / ROWS_PER_BLOCK;      // 256 -> one block per CU
    rpe_fused<<<grid, BLOCK_THREADS, 0, stream>>>(Q, pe, out);
}